// Round 1
// baseline (9047.704 us; speedup 1.0000x reference)
//
#include <hip/hip_runtime.h>
#include <hip/hip_bf16.h>

#define DH 128          // feature dim (D_IN == H == 128)
#define G3 384          // 3*H

// ---------------- degree ----------------
__global__ void deg_count_k(const int* __restrict__ ei, int E, unsigned* __restrict__ cnt) {
    int e = blockIdx.x * 256 + threadIdx.x;
    if (e < E) atomicAdd(&cnt[ei[E + e]], 1u);
}

__global__ void deg_finalize_k(const unsigned* __restrict__ cnt, int N,
                               float* __restrict__ deg, float* __restrict__ dinv) {
    int i = blockIdx.x * 256 + threadIdx.x;
    if (i < N) {
        float d = (float)cnt[i] + 1.0f;
        deg[i] = d;
        dinv[i] = rsqrtf(d);
    }
}

// ---------------- GEMM: C[N,128] = A[N,128] @ B[128,128] (B row-major [k][c]) ----------------
__global__ __launch_bounds__(256) void gemm128_k(const float* __restrict__ A,
                                                 const float* __restrict__ B,
                                                 float* __restrict__ C, int N) {
    __shared__ float Bs[DH * DH];     // 64 KB
    __shared__ float As[32 * DH];     // 16 KB
    int t = threadIdx.x;
    for (int i = t; i < DH * DH / 4; i += 256)
        ((float4*)Bs)[i] = ((const float4*)B)[i];
    size_t row0 = (size_t)blockIdx.x * 32;
    const float4* Ab = (const float4*)(A + row0 * DH);
    for (int i = t; i < 32 * DH / 4; i += 256)
        ((float4*)As)[i] = Ab[i];
    __syncthreads();

    int c = t & 127;
    int rg = t >> 7;                 // 0..1, 16 rows each
    const float* as = &As[rg * 16 * DH];
    float acc[16];
#pragma unroll
    for (int i = 0; i < 16; i++) acc[i] = 0.f;

    for (int k = 0; k < DH; k += 4) {
        float b0 = Bs[(k + 0) * DH + c];
        float b1 = Bs[(k + 1) * DH + c];
        float b2 = Bs[(k + 2) * DH + c];
        float b3 = Bs[(k + 3) * DH + c];
#pragma unroll
        for (int i = 0; i < 16; i++) {
            float4 a4 = *(const float4*)&as[i * DH + k];
            acc[i] = fmaf(a4.x, b0, acc[i]);
            acc[i] = fmaf(a4.y, b1, acc[i]);
            acc[i] = fmaf(a4.z, b2, acc[i]);
            acc[i] = fmaf(a4.w, b3, acc[i]);
        }
    }
#pragma unroll
    for (int i = 0; i < 16; i++)
        C[(row0 + rg * 16 + i) * DH + c] = acc[i];
}

// ---------------- edge scatter: agg[dst] += xw[src] * dinv[src]*dinv[dst] ----------------
__global__ void scatter_k(const int* __restrict__ ei, int E, const float* __restrict__ dinv,
                          const float* __restrict__ xw, float* __restrict__ agg) {
    long long gid = (long long)blockIdx.x * 256 + threadIdx.x;
    int e = (int)(gid >> 5);
    if (e >= E) return;
    int q = ((int)gid & 31) << 2;     // column offset 0..124
    int s = ei[e], d = ei[E + e];
    float nrm = dinv[s] * dinv[d];
    float4 v = *(const float4*)(xw + (size_t)s * DH + q);
    float* a = agg + (size_t)d * DH + q;
    unsafeAtomicAdd(a + 0, v.x * nrm);
    unsafeAtomicAdd(a + 1, v.y * nrm);
    unsafeAtomicAdd(a + 2, v.z * nrm);
    unsafeAtomicAdd(a + 3, v.w * nrm);
}

// ---------------- combine: dest = relu(agg + xw/deg + b) ----------------
__global__ void combine_k(const float* __restrict__ agg, const float* __restrict__ xw,
                          const float* __restrict__ dinv, const float* __restrict__ b,
                          float* __restrict__ dest, int N) {
    long long gid = (long long)blockIdx.x * 256 + threadIdx.x;
    if (gid >= (long long)N * DH) return;
    int row = (int)(gid >> 7);
    int c = (int)gid & 127;
    float di = dinv[row];
    float v = agg[gid] + xw[gid] * (di * di) + b[c];
    dest[gid] = fmaxf(v, 0.f);
}

// ---------------- fused GRU cell ----------------
// out = GRUCell(X, H) with torch semantics. 16 rows/block, 256 threads.
__global__ __launch_bounds__(256) void gru_k(const float* __restrict__ X,
                                             const float* __restrict__ Hs,
                                             const float* __restrict__ wih,
                                             const float* __restrict__ whh,
                                             const float* __restrict__ bih,
                                             const float* __restrict__ bhh,
                                             float* __restrict__ out, int N) {
    __shared__ float xs[16 * DH];
    __shared__ float hs[16 * DH];
    int t = threadIdx.x;
    size_t base = (size_t)blockIdx.x * 16 * DH;
    for (int i = t; i < 16 * DH / 4; i += 256) {
        ((float4*)xs)[i] = ((const float4*)(X + base))[i];
        ((float4*)hs)[i] = ((const float4*)(Hs + base))[i];
    }
    __syncthreads();

    int c = t & 127;
    int rg = t >> 7;                 // 0..1, 8 rows each
    const float* wr = wih + (size_t)c * DH;
    const float* wz = wih + (size_t)(DH + c) * DH;
    const float* wn = wih + (size_t)(2 * DH + c) * DH;
    const float* ur = whh + (size_t)c * DH;
    const float* uz = whh + (size_t)(DH + c) * DH;
    const float* un = whh + (size_t)(2 * DH + c) * DH;
    const float* xp = xs + rg * 8 * DH;
    const float* hp = hs + rg * 8 * DH;

    float air[8], aiz[8], ain[8], ahr[8], ahz[8], ahn[8];
#pragma unroll
    for (int i = 0; i < 8; i++) { air[i]=aiz[i]=ain[i]=ahr[i]=ahz[i]=ahn[i]=0.f; }

    for (int k = 0; k < DH; k += 4) {
        float4 wr4 = *(const float4*)(wr + k);
        float4 wz4 = *(const float4*)(wz + k);
        float4 wn4 = *(const float4*)(wn + k);
        float4 ur4 = *(const float4*)(ur + k);
        float4 uz4 = *(const float4*)(uz + k);
        float4 un4 = *(const float4*)(un + k);
#pragma unroll
        for (int i = 0; i < 8; i++) {
            float4 x4 = *(const float4*)(xp + i * DH + k);
            float4 h4 = *(const float4*)(hp + i * DH + k);
            air[i] = fmaf(x4.x, wr4.x, air[i]); air[i] = fmaf(x4.y, wr4.y, air[i]);
            air[i] = fmaf(x4.z, wr4.z, air[i]); air[i] = fmaf(x4.w, wr4.w, air[i]);
            aiz[i] = fmaf(x4.x, wz4.x, aiz[i]); aiz[i] = fmaf(x4.y, wz4.y, aiz[i]);
            aiz[i] = fmaf(x4.z, wz4.z, aiz[i]); aiz[i] = fmaf(x4.w, wz4.w, aiz[i]);
            ain[i] = fmaf(x4.x, wn4.x, ain[i]); ain[i] = fmaf(x4.y, wn4.y, ain[i]);
            ain[i] = fmaf(x4.z, wn4.z, ain[i]); ain[i] = fmaf(x4.w, wn4.w, ain[i]);
            ahr[i] = fmaf(h4.x, ur4.x, ahr[i]); ahr[i] = fmaf(h4.y, ur4.y, ahr[i]);
            ahr[i] = fmaf(h4.z, ur4.z, ahr[i]); ahr[i] = fmaf(h4.w, ur4.w, ahr[i]);
            ahz[i] = fmaf(h4.x, uz4.x, ahz[i]); ahz[i] = fmaf(h4.y, uz4.y, ahz[i]);
            ahz[i] = fmaf(h4.z, uz4.z, ahz[i]); ahz[i] = fmaf(h4.w, uz4.w, ahz[i]);
            ahn[i] = fmaf(h4.x, un4.x, ahn[i]); ahn[i] = fmaf(h4.y, un4.y, ahn[i]);
            ahn[i] = fmaf(h4.z, un4.z, ahn[i]); ahn[i] = fmaf(h4.w, un4.w, ahn[i]);
        }
    }

    float br = bih[c], bz = bih[DH + c], bn = bih[2 * DH + c];
    float cr = bhh[c], cz = bhh[DH + c], cn = bhh[2 * DH + c];
    size_t row0 = (size_t)blockIdx.x * 16 + rg * 8;
#pragma unroll
    for (int i = 0; i < 8; i++) {
        float r = 1.f / (1.f + expf(-(air[i] + br + ahr[i] + cr)));
        float z = 1.f / (1.f + expf(-(aiz[i] + bz + ahz[i] + cz)));
        float n = tanhf(ain[i] + bn + r * (ahn[i] + cn));
        float hv = hp[i * DH + c];
        out[(row0 + i) * DH + c] = (1.f - z) * n + z * hv;
    }
}

extern "C" void kernel_launch(void* const* d_in, const int* in_sizes, int n_in,
                              void* d_out, int out_size, void* d_ws, size_t ws_size,
                              hipStream_t stream) {
    const float* x    = (const float*)d_in[0];
    const int*   ei   = (const int*)d_in[1];
    const float* h1   = (const float*)d_in[2];
    const float* h2   = (const float*)d_in[3];
    const float* h3   = (const float*)d_in[4];
    const float* g1w  = (const float*)d_in[5];
    const float* g1b  = (const float*)d_in[6];
    const float* g2w  = (const float*)d_in[7];
    const float* g2b  = (const float*)d_in[8];
    const float* wih1 = (const float*)d_in[9];
    const float* whh1 = (const float*)d_in[10];
    const float* bih1 = (const float*)d_in[11];
    const float* bhh1 = (const float*)d_in[12];
    const float* wih2 = (const float*)d_in[13];
    const float* whh2 = (const float*)d_in[14];
    const float* bih2 = (const float*)d_in[15];
    const float* bhh2 = (const float*)d_in[16];
    const float* wih3 = (const float*)d_in[17];
    const float* whh3 = (const float*)d_in[18];
    const float* bih3 = (const float*)d_in[19];
    const float* bhh3 = (const float*)d_in[20];

    int N = in_sizes[0] / DH;
    int E = in_sizes[1] / 2;

    float* ws   = (float*)d_ws;
    unsigned* cnt = (unsigned*)ws;                 // N
    float* deg  = ws + N;                          // N
    float* dinv = ws + 2 * (size_t)N;              // N
    float* xw   = ws + 3 * (size_t)N;              // N*128
    float* agg  = xw + (size_t)N * DH;             // N*128
    float* x2   = agg + (size_t)N * DH;            // N*128

    float* out  = (float*)d_out;
    float* h1n  = out;
    float* h2n  = out + (size_t)N * DH;
    float* h3n  = out + 2 * (size_t)N * DH;

    // degree (shared by both GCN layers)
    hipMemsetAsync(cnt, 0, (size_t)N * 4, stream);
    hipMemsetAsync(agg, 0, (size_t)N * DH * 4, stream);
    deg_count_k<<<(E + 255) / 256, 256, 0, stream>>>(ei, E, cnt);
    deg_finalize_k<<<(N + 255) / 256, 256, 0, stream>>>(cnt, N, deg, dinv);

    // ---- GCN layer 1 ----
    gemm128_k<<<N / 32, 256, 0, stream>>>(x, g1w, xw, N);
    scatter_k<<<(int)(((long long)E * 32 + 255) / 256), 256, 0, stream>>>(ei, E, dinv, xw, agg);
    combine_k<<<(int)(((long long)N * DH + 255) / 256), 256, 0, stream>>>(agg, xw, dinv, g1b, x2, N);

    // ---- GCN layer 2 ----
    hipMemsetAsync(agg, 0, (size_t)N * DH * 4, stream);
    gemm128_k<<<N / 32, 256, 0, stream>>>(x2, g2w, xw, N);
    scatter_k<<<(int)(((long long)E * 32 + 255) / 256), 256, 0, stream>>>(ei, E, dinv, xw, agg);
    combine_k<<<(int)(((long long)N * DH + 255) / 256), 256, 0, stream>>>(agg, xw, dinv, g2b, x2, N);

    // ---- GRU chain ----
    gru_k<<<N / 16, 256, 0, stream>>>(x2,  h1, wih1, whh1, bih1, bhh1, h1n, N);
    gru_k<<<N / 16, 256, 0, stream>>>(h1n, h2, wih2, whh2, bih2, bhh2, h2n, N);
    gru_k<<<N / 16, 256, 0, stream>>>(h2n, h3, wih3, whh3, bih3, bhh3, h3n, N);
}

// Round 2
// 4036.711 us; speedup vs baseline: 2.2414x; 2.2414x over previous
//
#include <hip/hip_runtime.h>
#include <hip/hip_bf16.h>

#define DH 128          // feature dim (D_IN == H == 128)
#define SCAN_T 1024

// ---------------- degree histogram ----------------
__global__ void deg_count_k(const int* __restrict__ ei, int E, unsigned* __restrict__ cnt) {
    int e = blockIdx.x * 256 + threadIdx.x;
    if (e < E) atomicAdd(&cnt[ei[E + e]], 1u);
}

__global__ void dinv_k(const unsigned* __restrict__ cnt, int N, float* __restrict__ dinv) {
    int i = blockIdx.x * 256 + threadIdx.x;
    if (i < N) dinv[i] = rsqrtf((float)cnt[i] + 1.0f);
}

// ---------------- one-block exclusive scan over cnt -> offs (N+1), cur ----------------
__global__ __launch_bounds__(SCAN_T) void scan_k(const unsigned* __restrict__ cnt, int N,
                                                 int* __restrict__ offs, int* __restrict__ cur) {
    __shared__ int sums[SCAN_T];
    int t = threadIdx.x;
    int chunk = (N + SCAN_T - 1) / SCAN_T;
    int s0 = t * chunk;
    int s1 = min(s0 + chunk, N);
    int sum = 0;
    for (int i = s0; i < s1; ++i) sum += (int)cnt[i];
    sums[t] = sum;
    __syncthreads();
    for (int off = 1; off < SCAN_T; off <<= 1) {
        int v = (t >= off) ? sums[t - off] : 0;
        __syncthreads();
        sums[t] += v;
        __syncthreads();
    }
    int excl = (t == 0) ? 0 : sums[t - 1];
    for (int i = s0; i < s1; ++i) {
        offs[i] = excl;
        cur[i] = excl;
        excl += (int)cnt[i];
    }
    if (t == SCAN_T - 1) offs[N] = excl;
}

// ---------------- CSR fill: edges bucketed by dst ----------------
__global__ void fill_k(const int* __restrict__ ei, int E,
                       int* __restrict__ cur, int* __restrict__ csr_src) {
    int e = blockIdx.x * 256 + threadIdx.x;
    if (e < E) {
        int d = ei[E + e];
        int pos = atomicAdd(&cur[d], 1);
        csr_src[pos] = ei[e];
    }
}

// ---------------- GEMM: C[N,128] = A[N,128] @ B[128,128] (B row-major [k][c]) ----------------
__global__ __launch_bounds__(256) void gemm128_k(const float* __restrict__ A,
                                                 const float* __restrict__ B,
                                                 float* __restrict__ C, int N) {
    __shared__ float Bs[DH * DH];     // 64 KB
    __shared__ float As[32 * DH];     // 16 KB
    int t = threadIdx.x;
    for (int i = t; i < DH * DH / 4; i += 256)
        ((float4*)Bs)[i] = ((const float4*)B)[i];
    size_t row0 = (size_t)blockIdx.x * 32;
    const float4* Ab = (const float4*)(A + row0 * DH);
    for (int i = t; i < 32 * DH / 4; i += 256)
        ((float4*)As)[i] = Ab[i];
    __syncthreads();

    int c = t & 127;
    int rg = t >> 7;
    const float* as = &As[rg * 16 * DH];
    float acc[16];
#pragma unroll
    for (int i = 0; i < 16; i++) acc[i] = 0.f;

    for (int k = 0; k < DH; k += 4) {
        float b0 = Bs[(k + 0) * DH + c];
        float b1 = Bs[(k + 1) * DH + c];
        float b2 = Bs[(k + 2) * DH + c];
        float b3 = Bs[(k + 3) * DH + c];
#pragma unroll
        for (int i = 0; i < 16; i++) {
            float4 a4 = *(const float4*)&as[i * DH + k];
            acc[i] = fmaf(a4.x, b0, acc[i]);
            acc[i] = fmaf(a4.y, b1, acc[i]);
            acc[i] = fmaf(a4.z, b2, acc[i]);
            acc[i] = fmaf(a4.w, b3, acc[i]);
        }
    }
#pragma unroll
    for (int i = 0; i < 16; i++)
        C[(row0 + rg * 16 + i) * DH + c] = acc[i];
}

// ---------------- gather: dest[d] = relu( sum_e xw[src_e]*dinv[src_e]*dinv[d]
//                                          + xw[d]*dinv[d]^2 + b ) ----------------
// one wave per dst row; lane covers 2 contiguous columns (float2)
__global__ __launch_bounds__(256) void gather_k(const int* __restrict__ csr_src,
                                                const int* __restrict__ offs,
                                                const float* __restrict__ dinv,
                                                const float* __restrict__ xw,
                                                const float* __restrict__ bias,
                                                float* __restrict__ dest, int N) {
    int wid = blockIdx.x * 4 + (threadIdx.x >> 6);
    if (wid >= N) return;
    int lane = threadIdx.x & 63;
    int j = offs[wid];
    int end = offs[wid + 1];
    float dd = dinv[wid];
    const float2* xw2 = (const float2*)xw;
    float ax = 0.f, ay = 0.f;

    if (j < end) {
        int s = csr_src[j];
        float dv = dinv[s];
        for (; j + 1 < end; ++j) {
            int sn = csr_src[j + 1];          // prefetch next edge
            float dvn = dinv[sn];
            float2 v = xw2[(size_t)s * 64 + lane];
            float nrm = dd * dv;
            ax = fmaf(v.x, nrm, ax);
            ay = fmaf(v.y, nrm, ay);
            s = sn; dv = dvn;
        }
        float2 v = xw2[(size_t)s * 64 + lane];
        float nrm = dd * dv;
        ax = fmaf(v.x, nrm, ax);
        ay = fmaf(v.y, nrm, ay);
    }

    float2 xv = xw2[(size_t)wid * 64 + lane];
    float2 b2 = ((const float2*)bias)[lane];
    float sl = dd * dd;
    float ox = fmaxf(fmaf(xv.x, sl, ax) + b2.x, 0.f);
    float oy = fmaxf(fmaf(xv.y, sl, ay) + b2.y, 0.f);
    float2 o; o.x = ox; o.y = oy;
    ((float2*)dest)[(size_t)wid * 64 + lane] = o;
}

// ---------------- fused GRU cell ----------------
__global__ __launch_bounds__(256) void gru_k(const float* __restrict__ X,
                                             const float* __restrict__ Hs,
                                             const float* __restrict__ wih,
                                             const float* __restrict__ whh,
                                             const float* __restrict__ bih,
                                             const float* __restrict__ bhh,
                                             float* __restrict__ out, int N) {
    __shared__ float xs[16 * DH];
    __shared__ float hs[16 * DH];
    int t = threadIdx.x;
    size_t base = (size_t)blockIdx.x * 16 * DH;
    for (int i = t; i < 16 * DH / 4; i += 256) {
        ((float4*)xs)[i] = ((const float4*)(X + base))[i];
        ((float4*)hs)[i] = ((const float4*)(Hs + base))[i];
    }
    __syncthreads();

    int c = t & 127;
    int rg = t >> 7;
    const float* wr = wih + (size_t)c * DH;
    const float* wz = wih + (size_t)(DH + c) * DH;
    const float* wn = wih + (size_t)(2 * DH + c) * DH;
    const float* ur = whh + (size_t)c * DH;
    const float* uz = whh + (size_t)(DH + c) * DH;
    const float* un = whh + (size_t)(2 * DH + c) * DH;
    const float* xp = xs + rg * 8 * DH;
    const float* hp = hs + rg * 8 * DH;

    float air[8], aiz[8], ain[8], ahr[8], ahz[8], ahn[8];
#pragma unroll
    for (int i = 0; i < 8; i++) { air[i]=aiz[i]=ain[i]=ahr[i]=ahz[i]=ahn[i]=0.f; }

    for (int k = 0; k < DH; k += 4) {
        float4 wr4 = *(const float4*)(wr + k);
        float4 wz4 = *(const float4*)(wz + k);
        float4 wn4 = *(const float4*)(wn + k);
        float4 ur4 = *(const float4*)(ur + k);
        float4 uz4 = *(const float4*)(uz + k);
        float4 un4 = *(const float4*)(un + k);
#pragma unroll
        for (int i = 0; i < 8; i++) {
            float4 x4 = *(const float4*)(xp + i * DH + k);
            float4 h4 = *(const float4*)(hp + i * DH + k);
            air[i] = fmaf(x4.x, wr4.x, air[i]); air[i] = fmaf(x4.y, wr4.y, air[i]);
            air[i] = fmaf(x4.z, wr4.z, air[i]); air[i] = fmaf(x4.w, wr4.w, air[i]);
            aiz[i] = fmaf(x4.x, wz4.x, aiz[i]); aiz[i] = fmaf(x4.y, wz4.y, aiz[i]);
            aiz[i] = fmaf(x4.z, wz4.z, aiz[i]); aiz[i] = fmaf(x4.w, wz4.w, aiz[i]);
            ain[i] = fmaf(x4.x, wn4.x, ain[i]); ain[i] = fmaf(x4.y, wn4.y, ain[i]);
            ain[i] = fmaf(x4.z, wn4.z, ain[i]); ain[i] = fmaf(x4.w, wn4.w, ain[i]);
            ahr[i] = fmaf(h4.x, ur4.x, ahr[i]); ahr[i] = fmaf(h4.y, ur4.y, ahr[i]);
            ahr[i] = fmaf(h4.z, ur4.z, ahr[i]); ahr[i] = fmaf(h4.w, ur4.w, ahr[i]);
            ahz[i] = fmaf(h4.x, uz4.x, ahz[i]); ahz[i] = fmaf(h4.y, uz4.y, ahz[i]);
            ahz[i] = fmaf(h4.z, uz4.z, ahz[i]); ahz[i] = fmaf(h4.w, uz4.w, ahz[i]);
            ahn[i] = fmaf(h4.x, un4.x, ahn[i]); ahn[i] = fmaf(h4.y, un4.y, ahn[i]);
            ahn[i] = fmaf(h4.z, un4.z, ahn[i]); ahn[i] = fmaf(h4.w, un4.w, ahn[i]);
        }
    }

    float br = bih[c], bz = bih[DH + c], bn = bih[2 * DH + c];
    float cr = bhh[c], cz = bhh[DH + c], cn = bhh[2 * DH + c];
    size_t row0 = (size_t)blockIdx.x * 16 + rg * 8;
#pragma unroll
    for (int i = 0; i < 8; i++) {
        float r = 1.f / (1.f + expf(-(air[i] + br + ahr[i] + cr)));
        float z = 1.f / (1.f + expf(-(aiz[i] + bz + ahz[i] + cz)));
        float n = tanhf(ain[i] + bn + r * (ahn[i] + cn));
        float hv = hp[i * DH + c];
        out[(row0 + i) * DH + c] = (1.f - z) * n + z * hv;
    }
}

extern "C" void kernel_launch(void* const* d_in, const int* in_sizes, int n_in,
                              void* d_out, int out_size, void* d_ws, size_t ws_size,
                              hipStream_t stream) {
    const float* x    = (const float*)d_in[0];
    const int*   ei   = (const int*)d_in[1];
    const float* h1   = (const float*)d_in[2];
    const float* h2   = (const float*)d_in[3];
    const float* h3   = (const float*)d_in[4];
    const float* g1w  = (const float*)d_in[5];
    const float* g1b  = (const float*)d_in[6];
    const float* g2w  = (const float*)d_in[7];
    const float* g2b  = (const float*)d_in[8];
    const float* wih1 = (const float*)d_in[9];
    const float* whh1 = (const float*)d_in[10];
    const float* bih1 = (const float*)d_in[11];
    const float* bhh1 = (const float*)d_in[12];
    const float* wih2 = (const float*)d_in[13];
    const float* whh2 = (const float*)d_in[14];
    const float* bih2 = (const float*)d_in[15];
    const float* bhh2 = (const float*)d_in[16];
    const float* wih3 = (const float*)d_in[17];
    const float* whh3 = (const float*)d_in[18];
    const float* bih3 = (const float*)d_in[19];
    const float* bhh3 = (const float*)d_in[20];

    int N = in_sizes[0] / DH;
    int E = in_sizes[1] / 2;

    char* ws = (char*)d_ws;
    unsigned* cnt = (unsigned*)ws;                     ws += (size_t)N * 4;
    int* offs     = (int*)ws;                          ws += ((size_t)N + 1) * 4;
    int* cur      = (int*)ws;                          ws += (size_t)N * 4;
    float* dinv   = (float*)ws;                        ws += (size_t)N * 4;
    int* csr_src  = (int*)ws;                          ws += (size_t)E * 4;
    float* xw     = (float*)ws;                        ws += (size_t)N * DH * 4;
    float* x2     = (float*)ws;                        ws += (size_t)N * DH * 4;

    float* out  = (float*)d_out;
    float* h1n  = out;
    float* h2n  = out + (size_t)N * DH;
    float* h3n  = out + 2 * (size_t)N * DH;

    // ---- CSR build (per call; deterministic) ----
    hipMemsetAsync(cnt, 0, (size_t)N * 4, stream);
    deg_count_k<<<(E + 255) / 256, 256, 0, stream>>>(ei, E, cnt);
    dinv_k<<<(N + 255) / 256, 256, 0, stream>>>(cnt, N, dinv);
    scan_k<<<1, SCAN_T, 0, stream>>>(cnt, N, offs, cur);
    fill_k<<<(E + 255) / 256, 256, 0, stream>>>(ei, E, cur, csr_src);

    int gblocks = (N + 3) / 4;

    // ---- GCN layer 1 ----
    gemm128_k<<<N / 32, 256, 0, stream>>>(x, g1w, xw, N);
    gather_k<<<gblocks, 256, 0, stream>>>(csr_src, offs, dinv, xw, g1b, x2, N);

    // ---- GCN layer 2 ----
    gemm128_k<<<N / 32, 256, 0, stream>>>(x2, g2w, xw, N);
    gather_k<<<gblocks, 256, 0, stream>>>(csr_src, offs, dinv, xw, g2b, x2, N);

    // ---- GRU chain ----
    gru_k<<<N / 16, 256, 0, stream>>>(x2,  h1, wih1, whh1, bih1, bhh1, h1n, N);
    gru_k<<<N / 16, 256, 0, stream>>>(h1n, h2, wih2, whh2, bih2, bhh2, h2n, N);
    gru_k<<<N / 16, 256, 0, stream>>>(h2n, h3, wih3, whh3, bih3, bhh3, h3n, N);
}

// Round 3
// 1372.855 us; speedup vs baseline: 6.5904x; 2.9404x over previous
//
#include <hip/hip_runtime.h>
#include <hip/hip_bf16.h>

#define DH 128          // feature dim (D_IN == H == 128)
#define SCAN_T 1024

typedef __attribute__((ext_vector_type(8))) short short8_t;
typedef __attribute__((ext_vector_type(4))) float f32x4;

static __device__ __forceinline__ short f2bf(float f) {
    union { float f; unsigned u; } v; v.f = f;
    unsigned r = v.u + 0x7fffu + ((v.u >> 16) & 1u);   // RNE
    return (short)(r >> 16);
}

// ---------------- degree histogram ----------------
__global__ void deg_count_k(const int* __restrict__ ei, int E, unsigned* __restrict__ cnt) {
    int e = blockIdx.x * 256 + threadIdx.x;
    if (e < E) atomicAdd(&cnt[ei[E + e]], 1u);
}

__global__ void dinv_k(const unsigned* __restrict__ cnt, int N, float* __restrict__ dinv) {
    int i = blockIdx.x * 256 + threadIdx.x;
    if (i < N) dinv[i] = rsqrtf((float)cnt[i] + 1.0f);
}

// ---------------- one-block exclusive scan over cnt -> offs (N+1), cur ----------------
__global__ __launch_bounds__(SCAN_T) void scan_k(const unsigned* __restrict__ cnt, int N,
                                                 int* __restrict__ offs, int* __restrict__ cur) {
    __shared__ int sums[SCAN_T];
    int t = threadIdx.x;
    int chunk = (N + SCAN_T - 1) / SCAN_T;
    int s0 = t * chunk;
    int s1 = min(s0 + chunk, N);
    int sum = 0;
    for (int i = s0; i < s1; ++i) sum += (int)cnt[i];
    sums[t] = sum;
    __syncthreads();
    for (int off = 1; off < SCAN_T; off <<= 1) {
        int v = (t >= off) ? sums[t - off] : 0;
        __syncthreads();
        sums[t] += v;
        __syncthreads();
    }
    int excl = (t == 0) ? 0 : sums[t - 1];
    for (int i = s0; i < s1; ++i) {
        offs[i] = excl;
        cur[i] = excl;
        excl += (int)cnt[i];
    }
    if (t == SCAN_T - 1) offs[N] = excl;
}

// ---------------- CSR fill: edges bucketed by dst ----------------
__global__ void fill_k(const int* __restrict__ ei, int E,
                       int* __restrict__ cur, int* __restrict__ csr_src) {
    int e = blockIdx.x * 256 + threadIdx.x;
    if (e < E) {
        int d = ei[E + e];
        int pos = atomicAdd(&cur[d], 1);
        csr_src[pos] = ei[e];
    }
}

// ---------------- weight prep ----------------
__global__ void f2bf_k(const float* __restrict__ src, short* __restrict__ dst, int n) {
    int i = blockIdx.x * 256 + threadIdx.x;
    if (i < n) dst[i] = f2bf(src[i]);
}

// gcn weight [k][c] fp32 -> [c][k] bf16
__global__ void transpose_bf_k(const float* __restrict__ src, short* __restrict__ dst) {
    int i = blockIdx.x * 256 + threadIdx.x;   // 16384
    int c = i >> 7, k = i & 127;
    dst[i] = f2bf(src[k * DH + c]);
}

// ---------------- MFMA GEMM: C[N,128] = A[N,128] @ Wt^T, Wt bf16 [c][k] ----------------
__global__ __launch_bounds__(256) void gemm_mfma_k(const float* __restrict__ A,
                                                   const short* __restrict__ Wt,
                                                   float* __restrict__ C, int N) {
    int lane = threadIdx.x & 63;
    int row0 = blockIdx.x * 64 + (threadIdx.x >> 6) * 16;
    int lr = lane & 15, kg = lane >> 4;
    int arow = min(row0 + lr, N - 1);
    const float* ar = A + (size_t)arow * DH;
    short8_t af[4];
#pragma unroll
    for (int ks = 0; ks < 4; ks++) {
        const float* p = ar + ks * 32 + kg * 8;
        float4 a0 = *(const float4*)p;
        float4 a1 = *(const float4*)(p + 4);
        short8_t t;
        t[0] = f2bf(a0.x); t[1] = f2bf(a0.y); t[2] = f2bf(a0.z); t[3] = f2bf(a0.w);
        t[4] = f2bf(a1.x); t[5] = f2bf(a1.y); t[6] = f2bf(a1.z); t[7] = f2bf(a1.w);
        af[ks] = t;
    }
#pragma unroll
    for (int ct = 0; ct < 8; ct++) {
        const short* wr = Wt + (size_t)(ct * 16 + lr) * DH;
        f32x4 acc = {0.f, 0.f, 0.f, 0.f};
#pragma unroll
        for (int ks = 0; ks < 4; ks++) {
            short8_t b = *(const short8_t*)(wr + ks * 32 + kg * 8);
            acc = __builtin_amdgcn_mfma_f32_16x16x32_bf16(af[ks], b, acc, 0, 0, 0);
        }
        int col = ct * 16 + lr;
#pragma unroll
        for (int j = 0; j < 4; j++) {
            int grow = row0 + kg * 4 + j;
            if (grow < N) C[(size_t)grow * DH + col] = acc[j];
        }
    }
}

// ---------------- gather: dest[d] = relu( sum_e xw[src_e]*dinv[src_e]*dinv[d]
//                                          + xw[d]*dinv[d]^2 + b ) ----------------
__global__ __launch_bounds__(256) void gather_k(const int* __restrict__ csr_src,
                                                const int* __restrict__ offs,
                                                const float* __restrict__ dinv,
                                                const float* __restrict__ xw,
                                                const float* __restrict__ bias,
                                                float* __restrict__ dest, int N) {
    int wid = blockIdx.x * 4 + (threadIdx.x >> 6);
    if (wid >= N) return;
    int lane = threadIdx.x & 63;
    int j = offs[wid];
    int end = offs[wid + 1];
    float dd = dinv[wid];
    const float2* xw2 = (const float2*)xw;
    float ax = 0.f, ay = 0.f;

    if (j < end) {
        int s = csr_src[j];
        float dv = dinv[s];
        for (; j + 1 < end; ++j) {
            int sn = csr_src[j + 1];          // prefetch next edge
            float dvn = dinv[sn];
            float2 v = xw2[(size_t)s * 64 + lane];
            float nrm = dd * dv;
            ax = fmaf(v.x, nrm, ax);
            ay = fmaf(v.y, nrm, ay);
            s = sn; dv = dvn;
        }
        float2 v = xw2[(size_t)s * 64 + lane];
        float nrm = dd * dv;
        ax = fmaf(v.x, nrm, ax);
        ay = fmaf(v.y, nrm, ay);
    }

    float2 xv = xw2[(size_t)wid * 64 + lane];
    float2 b2 = ((const float2*)bias)[lane];
    float sl = dd * dd;
    float ox = fmaxf(fmaf(xv.x, sl, ax) + b2.x, 0.f);
    float oy = fmaxf(fmaf(xv.y, sl, ay) + b2.y, 0.f);
    float2 o; o.x = ox; o.y = oy;
    ((float2*)dest)[(size_t)wid * 64 + lane] = o;
}

// ---------------- fused MFMA GRU cell ----------------
// wih/whh: bf16 [384][128] row-major (torch layout, rows = out gate cols)
__global__ __launch_bounds__(256) void gru_mfma_k(const float* __restrict__ X,
                                                  const float* __restrict__ Hs,
                                                  const short* __restrict__ wih,
                                                  const short* __restrict__ whh,
                                                  const float* __restrict__ bih,
                                                  const float* __restrict__ bhh,
                                                  float* __restrict__ out, int N) {
    int lane = threadIdx.x & 63;
    int row0 = blockIdx.x * 64 + (threadIdx.x >> 6) * 16;
    int lr = lane & 15, kg = lane >> 4;
    int arow = min(row0 + lr, N - 1);
    const float* xr = X + (size_t)arow * DH;
    const float* hrp = Hs + (size_t)arow * DH;

    short8_t ax[4], ah[4];
#pragma unroll
    for (int ks = 0; ks < 4; ks++) {
        const float* p = xr + ks * 32 + kg * 8;
        float4 a0 = *(const float4*)p;
        float4 a1 = *(const float4*)(p + 4);
        short8_t t;
        t[0] = f2bf(a0.x); t[1] = f2bf(a0.y); t[2] = f2bf(a0.z); t[3] = f2bf(a0.w);
        t[4] = f2bf(a1.x); t[5] = f2bf(a1.y); t[6] = f2bf(a1.z); t[7] = f2bf(a1.w);
        ax[ks] = t;
        const float* q = hrp + ks * 32 + kg * 8;
        float4 h0 = *(const float4*)q;
        float4 h1 = *(const float4*)(q + 4);
        short8_t u;
        u[0] = f2bf(h0.x); u[1] = f2bf(h0.y); u[2] = f2bf(h0.z); u[3] = f2bf(h0.w);
        u[4] = f2bf(h1.x); u[5] = f2bf(h1.y); u[6] = f2bf(h1.z); u[7] = f2bf(h1.w);
        ah[ks] = u;
    }

    for (int cb = 0; cb < 4; cb++) {
        int c0 = cb * 32;
        f32x4 ai[3][2], ha[3][2];
#pragma unroll
        for (int g = 0; g < 3; g++)
#pragma unroll
            for (int hf = 0; hf < 2; hf++) {
                ai[g][hf] = (f32x4){0.f, 0.f, 0.f, 0.f};
                ha[g][hf] = (f32x4){0.f, 0.f, 0.f, 0.f};
            }
#pragma unroll
        for (int g = 0; g < 3; g++)
#pragma unroll
            for (int hf = 0; hf < 2; hf++) {
                const short* wi = wih + (size_t)(g * DH + c0 + hf * 16 + lr) * DH;
                const short* wh = whh + (size_t)(g * DH + c0 + hf * 16 + lr) * DH;
#pragma unroll
                for (int ks = 0; ks < 4; ks++) {
                    short8_t bi = *(const short8_t*)(wi + ks * 32 + kg * 8);
                    ai[g][hf] = __builtin_amdgcn_mfma_f32_16x16x32_bf16(ax[ks], bi, ai[g][hf], 0, 0, 0);
                    short8_t bh = *(const short8_t*)(wh + ks * 32 + kg * 8);
                    ha[g][hf] = __builtin_amdgcn_mfma_f32_16x16x32_bf16(ah[ks], bh, ha[g][hf], 0, 0, 0);
                }
            }
        // epilogue: gates + blend
#pragma unroll
        for (int hf = 0; hf < 2; hf++) {
            int gcol = c0 + hf * 16 + lr;
            float br = bih[gcol], bz = bih[DH + gcol], bn = bih[2 * DH + gcol];
            float cr = bhh[gcol], cz = bhh[DH + gcol], cn = bhh[2 * DH + gcol];
#pragma unroll
            for (int j = 0; j < 4; j++) {
                int grow = row0 + kg * 4 + j;
                if (grow < N) {
                    float hv = Hs[(size_t)grow * DH + gcol];
                    float rr = ai[0][hf][j] + br + ha[0][hf][j] + cr;
                    float zz = ai[1][hf][j] + bz + ha[1][hf][j] + cz;
                    float r = 1.f / (1.f + __expf(-rr));
                    float z = 1.f / (1.f + __expf(-zz));
                    float n = tanhf(ai[2][hf][j] + bn + r * (ha[2][hf][j] + cn));
                    out[(size_t)grow * DH + gcol] = (1.f - z) * n + z * hv;
                }
            }
        }
    }
}

extern "C" void kernel_launch(void* const* d_in, const int* in_sizes, int n_in,
                              void* d_out, int out_size, void* d_ws, size_t ws_size,
                              hipStream_t stream) {
    const float* x    = (const float*)d_in[0];
    const int*   ei   = (const int*)d_in[1];
    const float* h1   = (const float*)d_in[2];
    const float* h2   = (const float*)d_in[3];
    const float* h3   = (const float*)d_in[4];
    const float* g1w  = (const float*)d_in[5];
    const float* g1b  = (const float*)d_in[6];
    const float* g2w  = (const float*)d_in[7];
    const float* g2b  = (const float*)d_in[8];
    const float* wih1 = (const float*)d_in[9];
    const float* whh1 = (const float*)d_in[10];
    const float* bih1 = (const float*)d_in[11];
    const float* bhh1 = (const float*)d_in[12];
    const float* wih2 = (const float*)d_in[13];
    const float* whh2 = (const float*)d_in[14];
    const float* bih2 = (const float*)d_in[15];
    const float* bhh2 = (const float*)d_in[16];
    const float* wih3 = (const float*)d_in[17];
    const float* whh3 = (const float*)d_in[18];
    const float* bih3 = (const float*)d_in[19];
    const float* bhh3 = (const float*)d_in[20];

    int N = in_sizes[0] / DH;
    int E = in_sizes[1] / 2;

    char* wsp = (char*)d_ws;
    auto alloc = [&](size_t bytes) -> char* {
        char* p = wsp;
        wsp += (bytes + 63) & ~(size_t)63;
        return p;
    };
    unsigned* cnt = (unsigned*)alloc((size_t)N * 4);
    int* offs     = (int*)alloc(((size_t)N + 1) * 4);
    int* cur      = (int*)alloc((size_t)N * 4);
    float* dinv   = (float*)alloc((size_t)N * 4);
    int* csr_src  = (int*)alloc((size_t)E * 4);
    float* xw     = (float*)alloc((size_t)N * DH * 4);
    float* x2     = (float*)alloc((size_t)N * DH * 4);
    short* w1t    = (short*)alloc((size_t)DH * DH * 2);
    short* w2t    = (short*)alloc((size_t)DH * DH * 2);
    short* wb[6];
    for (int i = 0; i < 6; i++) wb[i] = (short*)alloc((size_t)3 * DH * DH * 2);

    float* out  = (float*)d_out;
    float* h1n  = out;
    float* h2n  = out + (size_t)N * DH;
    float* h3n  = out + 2 * (size_t)N * DH;

    // ---- weight prep (bf16) ----
    const int WN = 3 * DH * DH;      // 49152
    f2bf_k<<<(WN + 255) / 256, 256, 0, stream>>>(wih1, wb[0], WN);
    f2bf_k<<<(WN + 255) / 256, 256, 0, stream>>>(whh1, wb[1], WN);
    f2bf_k<<<(WN + 255) / 256, 256, 0, stream>>>(wih2, wb[2], WN);
    f2bf_k<<<(WN + 255) / 256, 256, 0, stream>>>(whh2, wb[3], WN);
    f2bf_k<<<(WN + 255) / 256, 256, 0, stream>>>(wih3, wb[4], WN);
    f2bf_k<<<(WN + 255) / 256, 256, 0, stream>>>(whh3, wb[5], WN);
    transpose_bf_k<<<(DH * DH + 255) / 256, 256, 0, stream>>>(g1w, w1t);
    transpose_bf_k<<<(DH * DH + 255) / 256, 256, 0, stream>>>(g2w, w2t);

    // ---- CSR build (per call; deterministic) ----
    hipMemsetAsync(cnt, 0, (size_t)N * 4, stream);
    deg_count_k<<<(E + 255) / 256, 256, 0, stream>>>(ei, E, cnt);
    dinv_k<<<(N + 255) / 256, 256, 0, stream>>>(cnt, N, dinv);
    scan_k<<<1, SCAN_T, 0, stream>>>(cnt, N, offs, cur);
    fill_k<<<(E + 255) / 256, 256, 0, stream>>>(ei, E, cur, csr_src);

    int nblk64 = (N + 63) / 64;
    int gblocks = (N + 3) / 4;

    // ---- GCN layer 1 ----
    gemm_mfma_k<<<nblk64, 256, 0, stream>>>(x, w1t, xw, N);
    gather_k<<<gblocks, 256, 0, stream>>>(csr_src, offs, dinv, xw, g1b, x2, N);

    // ---- GCN layer 2 ----
    gemm_mfma_k<<<nblk64, 256, 0, stream>>>(x2, w2t, xw, N);
    gather_k<<<gblocks, 256, 0, stream>>>(csr_src, offs, dinv, xw, g2b, x2, N);

    // ---- GRU chain ----
    gru_mfma_k<<<nblk64, 256, 0, stream>>>(x2,  h1, wb[0], wb[1], bih1, bhh1, h1n, N);
    gru_mfma_k<<<nblk64, 256, 0, stream>>>(h1n, h2, wb[2], wb[3], bih2, bhh2, h2n, N);
    gru_mfma_k<<<nblk64, 256, 0, stream>>>(h2n, h3, wb[4], wb[5], bih3, bhh3, h3n, N);
}

// Round 4
// 1099.203 us; speedup vs baseline: 8.2312x; 1.2490x over previous
//
#include <hip/hip_runtime.h>
#include <hip/hip_bf16.h>

#define DH 128          // feature dim (D_IN == H == 128)
#define SCB 1024        // scan elements per block

typedef __attribute__((ext_vector_type(8))) short short8_t;
typedef __attribute__((ext_vector_type(4))) float f32x4;

static __device__ __forceinline__ short f2bf(float f) {
    union { float f; unsigned u; } v; v.f = f;
    unsigned r = v.u + 0x7fffu + ((v.u >> 16) & 1u);   // RNE
    return (short)(r >> 16);
}

// ---------------- degree histogram ----------------
__global__ void deg_count_k(const int* __restrict__ ei, int E, unsigned* __restrict__ cnt) {
    int e = blockIdx.x * 256 + threadIdx.x;
    if (e < E) atomicAdd(&cnt[ei[E + e]], 1u);
}

// ---------------- 3-phase grid-parallel exclusive scan ----------------
// phase 1: per-block local exclusive prefix (4 elems/thread) + block sums
__global__ __launch_bounds__(256) void scan1_k(const unsigned* __restrict__ cnt, int N,
                                               int* __restrict__ offs, unsigned* __restrict__ bsum) {
    __shared__ unsigned s[256];
    int t = threadIdx.x;
    int i0 = blockIdx.x * SCB + t * 4;
    unsigned v0 = (i0 + 0 < N) ? cnt[i0 + 0] : 0u;
    unsigned v1 = (i0 + 1 < N) ? cnt[i0 + 1] : 0u;
    unsigned v2 = (i0 + 2 < N) ? cnt[i0 + 2] : 0u;
    unsigned v3 = (i0 + 3 < N) ? cnt[i0 + 3] : 0u;
    unsigned ts = v0 + v1 + v2 + v3;
    s[t] = ts;
    __syncthreads();
    for (int off = 1; off < 256; off <<= 1) {
        unsigned u = (t >= off) ? s[t - off] : 0u;
        __syncthreads();
        s[t] += u;
        __syncthreads();
    }
    unsigned ex = s[t] - ts;
    if (i0 + 0 < N) offs[i0 + 0] = (int)ex;
    if (i0 + 1 < N) offs[i0 + 1] = (int)(ex + v0);
    if (i0 + 2 < N) offs[i0 + 2] = (int)(ex + v0 + v1);
    if (i0 + 3 < N) offs[i0 + 3] = (int)(ex + v0 + v1 + v2);
    if (t == 255) bsum[blockIdx.x] = s[255];
}

// phase 2: scan block sums (B <= 1024), bsum becomes exclusive; bsum[B] = total
__global__ __launch_bounds__(1024) void scan2_k(unsigned* __restrict__ bsum, int B) {
    __shared__ unsigned s[1024];
    int t = threadIdx.x;
    unsigned v = (t < B) ? bsum[t] : 0u;
    s[t] = v;
    __syncthreads();
    for (int off = 1; off < 1024; off <<= 1) {
        unsigned u = (t >= off) ? s[t - off] : 0u;
        __syncthreads();
        s[t] += u;
        __syncthreads();
    }
    if (t < B) bsum[t] = s[t] - v;
    if (t == 0) bsum[B] = s[1023];
}

// phase 3: add block base; produce cur copy + dinv + offs[N]
__global__ void scan3_k(int* __restrict__ offs, int* __restrict__ cur,
                        float* __restrict__ dinv, const unsigned* __restrict__ cnt,
                        const unsigned* __restrict__ bsum, int N, int B) {
    int i = blockIdx.x * 256 + threadIdx.x;
    if (i < N) {
        int v = offs[i] + (int)bsum[i >> 10];
        offs[i] = v;
        cur[i] = v;
        dinv[i] = rsqrtf((float)cnt[i] + 1.0f);
    }
    if (i == 0) offs[N] = (int)bsum[B];
}

// ---------------- CSR fill: edges bucketed by dst ----------------
__global__ void fill_k(const int* __restrict__ ei, int E,
                       int* __restrict__ cur, int* __restrict__ csr_src) {
    int e = blockIdx.x * 256 + threadIdx.x;
    if (e < E) {
        int d = ei[E + e];
        int pos = atomicAdd(&cur[d], 1);
        csr_src[pos] = ei[e];
    }
}

// ---------------- weight prep ----------------
// six GRU weight mats fp32 -> bf16, one launch
__global__ void f2bf6_k(const float* __restrict__ s0, const float* __restrict__ s1,
                        const float* __restrict__ s2, const float* __restrict__ s3,
                        const float* __restrict__ s4, const float* __restrict__ s5,
                        short* __restrict__ dst, int WN) {
    int i = blockIdx.x * 256 + threadIdx.x;
    if (i >= 6 * WN) return;
    int b = i / WN, r = i - b * WN;
    const float* srcs[6] = {s0, s1, s2, s3, s4, s5};
    dst[i] = f2bf(srcs[b][r]);
}

// gcn weight [k][c] fp32 -> [c][k] bf16 (two mats in one launch)
__global__ void transpose_bf2_k(const float* __restrict__ sa, const float* __restrict__ sb,
                                short* __restrict__ da, short* __restrict__ db) {
    int i = blockIdx.x * 256 + threadIdx.x;   // 2*16384
    int m = i >> 14;
    int j = i & 16383;
    int c = j >> 7, k = j & 127;
    const float* s = m ? sb : sa;
    short* d = m ? db : da;
    d[j] = f2bf(s[k * DH + c]);
}

// ---------------- MFMA GEMM: C[N,128] = A[N,128] @ Wt^T, Wt bf16 [c][k] ----------------
__global__ __launch_bounds__(256) void gemm_mfma_k(const float* __restrict__ A,
                                                   const short* __restrict__ Wt,
                                                   float* __restrict__ C, int N) {
    int lane = threadIdx.x & 63;
    int row0 = blockIdx.x * 64 + (threadIdx.x >> 6) * 16;
    int lr = lane & 15, kg = lane >> 4;
    int arow = min(row0 + lr, N - 1);
    const float* ar = A + (size_t)arow * DH;
    short8_t af[4];
#pragma unroll
    for (int ks = 0; ks < 4; ks++) {
        const float* p = ar + ks * 32 + kg * 8;
        float4 a0 = *(const float4*)p;
        float4 a1 = *(const float4*)(p + 4);
        short8_t t;
        t[0] = f2bf(a0.x); t[1] = f2bf(a0.y); t[2] = f2bf(a0.z); t[3] = f2bf(a0.w);
        t[4] = f2bf(a1.x); t[5] = f2bf(a1.y); t[6] = f2bf(a1.z); t[7] = f2bf(a1.w);
        af[ks] = t;
    }
#pragma unroll
    for (int ct = 0; ct < 8; ct++) {
        const short* wr = Wt + (size_t)(ct * 16 + lr) * DH;
        f32x4 acc = {0.f, 0.f, 0.f, 0.f};
#pragma unroll
        for (int ks = 0; ks < 4; ks++) {
            short8_t b = *(const short8_t*)(wr + ks * 32 + kg * 8);
            acc = __builtin_amdgcn_mfma_f32_16x16x32_bf16(af[ks], b, acc, 0, 0, 0);
        }
        int col = ct * 16 + lr;
#pragma unroll
        for (int j = 0; j < 4; j++) {
            int grow = row0 + kg * 4 + j;
            if (grow < N) C[(size_t)grow * DH + col] = acc[j];
        }
    }
}

// ---------------- gather: dest[d] = relu( sum_e xw[src_e]*dinv[src_e]*dinv[d]
//                                          + xw[d]*dinv[d]^2 + b ) ----------------
__global__ __launch_bounds__(256) void gather_k(const int* __restrict__ csr_src,
                                                const int* __restrict__ offs,
                                                const float* __restrict__ dinv,
                                                const float* __restrict__ xw,
                                                const float* __restrict__ bias,
                                                float* __restrict__ dest, int N) {
    int wid = blockIdx.x * 4 + (threadIdx.x >> 6);
    if (wid >= N) return;
    int lane = threadIdx.x & 63;
    int j = offs[wid];
    int end = offs[wid + 1];
    float dd = dinv[wid];
    const float2* xw2 = (const float2*)xw;
    float ax = 0.f, ay = 0.f;

    if (j < end) {
        int s = csr_src[j];
        float dv = dinv[s];
        for (; j + 1 < end; ++j) {
            int sn = csr_src[j + 1];          // prefetch next edge
            float dvn = dinv[sn];
            float2 v = xw2[(size_t)s * 64 + lane];
            float nrm = dd * dv;
            ax = fmaf(v.x, nrm, ax);
            ay = fmaf(v.y, nrm, ay);
            s = sn; dv = dvn;
        }
        float2 v = xw2[(size_t)s * 64 + lane];
        float nrm = dd * dv;
        ax = fmaf(v.x, nrm, ax);
        ay = fmaf(v.y, nrm, ay);
    }

    float2 xv = xw2[(size_t)wid * 64 + lane];
    float2 b2 = ((const float2*)bias)[lane];
    float sl = dd * dd;
    float ox = fmaxf(fmaf(xv.x, sl, ax) + b2.x, 0.f);
    float oy = fmaxf(fmaf(xv.y, sl, ay) + b2.y, 0.f);
    float2 o; o.x = ox; o.y = oy;
    ((float2*)dest)[(size_t)wid * 64 + lane] = o;
}

// ---------------- fused MFMA GRU cell ----------------
// wih/whh: bf16 [384][128] row-major (torch layout, rows = out gate cols)
__global__ __launch_bounds__(256) void gru_mfma_k(const float* __restrict__ X,
                                                  const float* __restrict__ Hs,
                                                  const short* __restrict__ wih,
                                                  const short* __restrict__ whh,
                                                  const float* __restrict__ bih,
                                                  const float* __restrict__ bhh,
                                                  float* __restrict__ out, int N) {
    int lane = threadIdx.x & 63;
    int row0 = blockIdx.x * 64 + (threadIdx.x >> 6) * 16;
    int lr = lane & 15, kg = lane >> 4;
    int arow = min(row0 + lr, N - 1);
    const float* xr = X + (size_t)arow * DH;
    const float* hrp = Hs + (size_t)arow * DH;

    short8_t ax[4], ah[4];
#pragma unroll
    for (int ks = 0; ks < 4; ks++) {
        const float* p = xr + ks * 32 + kg * 8;
        float4 a0 = *(const float4*)p;
        float4 a1 = *(const float4*)(p + 4);
        short8_t t;
        t[0] = f2bf(a0.x); t[1] = f2bf(a0.y); t[2] = f2bf(a0.z); t[3] = f2bf(a0.w);
        t[4] = f2bf(a1.x); t[5] = f2bf(a1.y); t[6] = f2bf(a1.z); t[7] = f2bf(a1.w);
        ax[ks] = t;
        const float* q = hrp + ks * 32 + kg * 8;
        float4 h0 = *(const float4*)q;
        float4 h1 = *(const float4*)(q + 4);
        short8_t u;
        u[0] = f2bf(h0.x); u[1] = f2bf(h0.y); u[2] = f2bf(h0.z); u[3] = f2bf(h0.w);
        u[4] = f2bf(h1.x); u[5] = f2bf(h1.y); u[6] = f2bf(h1.z); u[7] = f2bf(h1.w);
        ah[ks] = u;
    }

    for (int cb = 0; cb < 4; cb++) {
        int c0 = cb * 32;
        f32x4 ai[3][2], ha[3][2];
#pragma unroll
        for (int g = 0; g < 3; g++)
#pragma unroll
            for (int hf = 0; hf < 2; hf++) {
                ai[g][hf] = (f32x4){0.f, 0.f, 0.f, 0.f};
                ha[g][hf] = (f32x4){0.f, 0.f, 0.f, 0.f};
            }
#pragma unroll
        for (int g = 0; g < 3; g++)
#pragma unroll
            for (int hf = 0; hf < 2; hf++) {
                const short* wi = wih + (size_t)(g * DH + c0 + hf * 16 + lr) * DH;
                const short* wh = whh + (size_t)(g * DH + c0 + hf * 16 + lr) * DH;
#pragma unroll
                for (int ks = 0; ks < 4; ks++) {
                    short8_t bi = *(const short8_t*)(wi + ks * 32 + kg * 8);
                    ai[g][hf] = __builtin_amdgcn_mfma_f32_16x16x32_bf16(ax[ks], bi, ai[g][hf], 0, 0, 0);
                    short8_t bh = *(const short8_t*)(wh + ks * 32 + kg * 8);
                    ha[g][hf] = __builtin_amdgcn_mfma_f32_16x16x32_bf16(ah[ks], bh, ha[g][hf], 0, 0, 0);
                }
            }
        // epilogue: gates + blend
#pragma unroll
        for (int hf = 0; hf < 2; hf++) {
            int gcol = c0 + hf * 16 + lr;
            float br = bih[gcol], bz = bih[DH + gcol], bn = bih[2 * DH + gcol];
            float cr = bhh[gcol], cz = bhh[DH + gcol], cn = bhh[2 * DH + gcol];
#pragma unroll
            for (int j = 0; j < 4; j++) {
                int grow = row0 + kg * 4 + j;
                if (grow < N) {
                    float hv = Hs[(size_t)grow * DH + gcol];
                    float rr = ai[0][hf][j] + br + ha[0][hf][j] + cr;
                    float zz = ai[1][hf][j] + bz + ha[1][hf][j] + cz;
                    float r = 1.f / (1.f + __expf(-rr));
                    float z = 1.f / (1.f + __expf(-zz));
                    float n = tanhf(ai[2][hf][j] + bn + r * (ha[2][hf][j] + cn));
                    out[(size_t)grow * DH + gcol] = (1.f - z) * n + z * hv;
                }
            }
        }
    }
}

extern "C" void kernel_launch(void* const* d_in, const int* in_sizes, int n_in,
                              void* d_out, int out_size, void* d_ws, size_t ws_size,
                              hipStream_t stream) {
    const float* x    = (const float*)d_in[0];
    const int*   ei   = (const int*)d_in[1];
    const float* h1   = (const float*)d_in[2];
    const float* h2   = (const float*)d_in[3];
    const float* h3   = (const float*)d_in[4];
    const float* g1w  = (const float*)d_in[5];
    const float* g1b  = (const float*)d_in[6];
    const float* g2w  = (const float*)d_in[7];
    const float* g2b  = (const float*)d_in[8];
    const float* wih1 = (const float*)d_in[9];
    const float* whh1 = (const float*)d_in[10];
    const float* bih1 = (const float*)d_in[11];
    const float* bhh1 = (const float*)d_in[12];
    const float* wih2 = (const float*)d_in[13];
    const float* whh2 = (const float*)d_in[14];
    const float* bih2 = (const float*)d_in[15];
    const float* bhh2 = (const float*)d_in[16];
    const float* wih3 = (const float*)d_in[17];
    const float* whh3 = (const float*)d_in[18];
    const float* bih3 = (const float*)d_in[19];
    const float* bhh3 = (const float*)d_in[20];

    int N = in_sizes[0] / DH;
    int E = in_sizes[1] / 2;
    int B = (N + SCB - 1) / SCB;

    char* wsp = (char*)d_ws;
    auto alloc = [&](size_t bytes) -> char* {
        char* p = wsp;
        wsp += (bytes + 63) & ~(size_t)63;
        return p;
    };
    unsigned* cnt = (unsigned*)alloc((size_t)N * 4);
    int* offs     = (int*)alloc(((size_t)N + 1) * 4);
    int* cur      = (int*)alloc((size_t)N * 4);
    float* dinv   = (float*)alloc((size_t)N * 4);
    unsigned* bsum= (unsigned*)alloc(((size_t)B + 1) * 4);
    int* csr_src  = (int*)alloc((size_t)E * 4);
    float* xw     = (float*)alloc((size_t)N * DH * 4);
    float* x2     = (float*)alloc((size_t)N * DH * 4);
    short* w1t    = (short*)alloc((size_t)DH * DH * 2);
    short* w2t    = (short*)alloc((size_t)DH * DH * 2);
    const int WN = 3 * DH * DH;      // 49152
    short* wbAll  = (short*)alloc((size_t)6 * WN * 2);
    short* wb[6];
    for (int i = 0; i < 6; i++) wb[i] = wbAll + (size_t)i * WN;

    float* out  = (float*)d_out;
    float* h1n  = out;
    float* h2n  = out + (size_t)N * DH;
    float* h3n  = out + 2 * (size_t)N * DH;

    // ---- weight prep (bf16) ----
    f2bf6_k<<<(6 * WN + 255) / 256, 256, 0, stream>>>(wih1, whh1, wih2, whh2, wih3, whh3, wbAll, WN);
    transpose_bf2_k<<<(2 * DH * DH + 255) / 256, 256, 0, stream>>>(g1w, g2w, w1t, w2t);

    // ---- CSR build (per call; deterministic) ----
    hipMemsetAsync(cnt, 0, (size_t)N * 4, stream);
    deg_count_k<<<(E + 255) / 256, 256, 0, stream>>>(ei, E, cnt);
    scan1_k<<<B, 256, 0, stream>>>(cnt, N, offs, bsum);
    scan2_k<<<1, 1024, 0, stream>>>(bsum, B);
    scan3_k<<<(N + 255) / 256, 256, 0, stream>>>(offs, cur, dinv, cnt, bsum, N, B);
    fill_k<<<(E + 255) / 256, 256, 0, stream>>>(ei, E, cur, csr_src);

    int nblk64 = (N + 63) / 64;
    int gblocks = (N + 3) / 4;

    // ---- GCN layer 1 ----
    gemm_mfma_k<<<nblk64, 256, 0, stream>>>(x, w1t, xw, N);
    gather_k<<<gblocks, 256, 0, stream>>>(csr_src, offs, dinv, xw, g1b, x2, N);

    // ---- GCN layer 2 ----
    gemm_mfma_k<<<nblk64, 256, 0, stream>>>(x2, w2t, xw, N);
    gather_k<<<gblocks, 256, 0, stream>>>(csr_src, offs, dinv, xw, g2b, x2, N);

    // ---- GRU chain ----
    gru_mfma_k<<<nblk64, 256, 0, stream>>>(x2,  h1, wb[0], wb[1], bih1, bhh1, h1n, N);
    gru_mfma_k<<<nblk64, 256, 0, stream>>>(h1n, h2, wb[2], wb[3], bih2, bhh2, h2n, N);
    gru_mfma_k<<<nblk64, 256, 0, stream>>>(h2n, h3, wb[4], wb[5], bih3, bhh3, h3n, N);
}

// Round 5
// 953.672 us; speedup vs baseline: 9.4872x; 1.1526x over previous
//
#include <hip/hip_runtime.h>
#include <hip/hip_bf16.h>

#define DH 128          // feature dim (D_IN == H == 128)
#define SCB 1024        // scan elements per block

typedef __attribute__((ext_vector_type(8))) short short8_t;
typedef __attribute__((ext_vector_type(4))) float f32x4;

static __device__ __forceinline__ short f2bf(float f) {
    union { float f; unsigned u; } v; v.f = f;
    unsigned r = v.u + 0x7fffu + ((v.u >> 16) & 1u);   // RNE
    return (short)(r >> 16);
}

static __device__ __forceinline__ short8_t cvt8(const float* p) {
    float4 a0 = *(const float4*)p;
    float4 a1 = *(const float4*)(p + 4);
    short8_t t;
    t[0] = f2bf(a0.x); t[1] = f2bf(a0.y); t[2] = f2bf(a0.z); t[3] = f2bf(a0.w);
    t[4] = f2bf(a1.x); t[5] = f2bf(a1.y); t[6] = f2bf(a1.z); t[7] = f2bf(a1.w);
    return t;
}

// ---------------- degree histogram ----------------
__global__ void deg_count_k(const int* __restrict__ ei, int E, unsigned* __restrict__ cnt) {
    int e = blockIdx.x * 256 + threadIdx.x;
    if (e < E) atomicAdd(&cnt[ei[E + e]], 1u);
}

// ---------------- 3-phase grid-parallel exclusive scan ----------------
__global__ __launch_bounds__(256) void scan1_k(const unsigned* __restrict__ cnt, int N,
                                               int* __restrict__ offs, unsigned* __restrict__ bsum) {
    __shared__ unsigned s[256];
    int t = threadIdx.x;
    int i0 = blockIdx.x * SCB + t * 4;
    unsigned v0 = (i0 + 0 < N) ? cnt[i0 + 0] : 0u;
    unsigned v1 = (i0 + 1 < N) ? cnt[i0 + 1] : 0u;
    unsigned v2 = (i0 + 2 < N) ? cnt[i0 + 2] : 0u;
    unsigned v3 = (i0 + 3 < N) ? cnt[i0 + 3] : 0u;
    unsigned ts = v0 + v1 + v2 + v3;
    s[t] = ts;
    __syncthreads();
    for (int off = 1; off < 256; off <<= 1) {
        unsigned u = (t >= off) ? s[t - off] : 0u;
        __syncthreads();
        s[t] += u;
        __syncthreads();
    }
    unsigned ex = s[t] - ts;
    if (i0 + 0 < N) offs[i0 + 0] = (int)ex;
    if (i0 + 1 < N) offs[i0 + 1] = (int)(ex + v0);
    if (i0 + 2 < N) offs[i0 + 2] = (int)(ex + v0 + v1);
    if (i0 + 3 < N) offs[i0 + 3] = (int)(ex + v0 + v1 + v2);
    if (t == 255) bsum[blockIdx.x] = s[255];
}

__global__ __launch_bounds__(1024) void scan2_k(unsigned* __restrict__ bsum, int B) {
    __shared__ unsigned s[1024];
    int t = threadIdx.x;
    unsigned v = (t < B) ? bsum[t] : 0u;
    s[t] = v;
    __syncthreads();
    for (int off = 1; off < 1024; off <<= 1) {
        unsigned u = (t >= off) ? s[t - off] : 0u;
        __syncthreads();
        s[t] += u;
        __syncthreads();
    }
    if (t < B) bsum[t] = s[t] - v;
    if (t == 0) bsum[B] = s[1023];
}

__global__ void scan3_k(int* __restrict__ offs, int* __restrict__ cur,
                        float* __restrict__ dinv, const unsigned* __restrict__ cnt,
                        const unsigned* __restrict__ bsum, int N, int B) {
    int i = blockIdx.x * 256 + threadIdx.x;
    if (i < N) {
        int v = offs[i] + (int)bsum[i >> 10];
        offs[i] = v;
        cur[i] = v;
        dinv[i] = rsqrtf((float)cnt[i] + 1.0f);
    }
    if (i == 0) offs[N] = (int)bsum[B];
}

// ---------------- CSR fill: edges bucketed by dst ----------------
__global__ void fill_k(const int* __restrict__ ei, int E,
                       int* __restrict__ cur, int* __restrict__ csr_src) {
    int e = blockIdx.x * 256 + threadIdx.x;
    if (e < E) {
        int d = ei[E + e];
        int pos = atomicAdd(&cur[d], 1);
        csr_src[pos] = ei[e];
    }
}

// ---------------- weight prep ----------------
__global__ void f2bf6_k(const float* __restrict__ s0, const float* __restrict__ s1,
                        const float* __restrict__ s2, const float* __restrict__ s3,
                        const float* __restrict__ s4, const float* __restrict__ s5,
                        short* __restrict__ dst, int WN) {
    int i = blockIdx.x * 256 + threadIdx.x;
    if (i >= 6 * WN) return;
    int b = i / WN, r = i - b * WN;
    const float* srcs[6] = {s0, s1, s2, s3, s4, s5};
    dst[i] = f2bf(srcs[b][r]);
}

__global__ void transpose_bf2_k(const float* __restrict__ sa, const float* __restrict__ sb,
                                short* __restrict__ da, short* __restrict__ db) {
    int i = blockIdx.x * 256 + threadIdx.x;   // 2*16384
    int m = i >> 14;
    int j = i & 16383;
    int c = j >> 7, k = j & 127;
    const float* s = m ? sb : sa;
    short* d = m ? db : da;
    d[j] = f2bf(s[k * DH + c]);
}

// ---------------- MFMA GEMM: C[N,128] = A[N,128] @ Wt^T, Wt bf16 [c][k] ----------------
// 128 rows/block, 4 waves, 2 row-tiles/wave (B-fragment reused 2x)
__global__ __launch_bounds__(256, 2) void gemm_mfma_k(const float* __restrict__ A,
                                                      const short* __restrict__ Wt,
                                                      float* __restrict__ C, int N) {
    int lane = threadIdx.x & 63;
    int row0 = blockIdx.x * 128 + (threadIdx.x >> 6) * 32;
    int lr = lane & 15, kg = lane >> 4;
    int ar0 = min(row0 + lr, N - 1);
    int ar1 = min(row0 + 16 + lr, N - 1);
    const float* a0p = A + (size_t)ar0 * DH;
    const float* a1p = A + (size_t)ar1 * DH;
    short8_t af[2][4];
#pragma unroll
    for (int ks = 0; ks < 4; ks++) {
        af[0][ks] = cvt8(a0p + ks * 32 + kg * 8);
        af[1][ks] = cvt8(a1p + ks * 32 + kg * 8);
    }
#pragma unroll
    for (int ct = 0; ct < 8; ct++) {
        const short* wr = Wt + (size_t)(ct * 16 + lr) * DH;
        short8_t b[4];
#pragma unroll
        for (int ks = 0; ks < 4; ks++) b[ks] = *(const short8_t*)(wr + ks * 32 + kg * 8);
        f32x4 acc0 = {0.f, 0.f, 0.f, 0.f};
        f32x4 acc1 = {0.f, 0.f, 0.f, 0.f};
#pragma unroll
        for (int ks = 0; ks < 4; ks++) {
            acc0 = __builtin_amdgcn_mfma_f32_16x16x32_bf16(af[0][ks], b[ks], acc0, 0, 0, 0);
            acc1 = __builtin_amdgcn_mfma_f32_16x16x32_bf16(af[1][ks], b[ks], acc1, 0, 0, 0);
        }
        int col = ct * 16 + lr;
#pragma unroll
        for (int j = 0; j < 4; j++) {
            int g0 = row0 + kg * 4 + j;
            int g1 = row0 + 16 + kg * 4 + j;
            if (g0 < N) C[(size_t)g0 * DH + col] = acc0[j];
            if (g1 < N) C[(size_t)g1 * DH + col] = acc1[j];
        }
    }
}

// ---------------- gather: dest[d] = relu( sum_e xw[src_e]*dinv[src_e]*dinv[d]
//                                          + xw[d]*dinv[d]^2 + b ) ----------------
__global__ __launch_bounds__(256) void gather_k(const int* __restrict__ csr_src,
                                                const int* __restrict__ offs,
                                                const float* __restrict__ dinv,
                                                const float* __restrict__ xw,
                                                const float* __restrict__ bias,
                                                float* __restrict__ dest, int N) {
    int wid = blockIdx.x * 4 + (threadIdx.x >> 6);
    if (wid >= N) return;
    int lane = threadIdx.x & 63;
    int j = offs[wid];
    int end = offs[wid + 1];
    float dd = dinv[wid];
    const float2* xw2 = (const float2*)xw;
    float ax = 0.f, ay = 0.f;

    if (j < end) {
        int s = csr_src[j];
        float dv = dinv[s];
        for (; j + 1 < end; ++j) {
            int sn = csr_src[j + 1];          // prefetch next edge
            float dvn = dinv[sn];
            float2 v = xw2[(size_t)s * 64 + lane];
            float nrm = dd * dv;
            ax = fmaf(v.x, nrm, ax);
            ay = fmaf(v.y, nrm, ay);
            s = sn; dv = dvn;
        }
        float2 v = xw2[(size_t)s * 64 + lane];
        float nrm = dd * dv;
        ax = fmaf(v.x, nrm, ax);
        ay = fmaf(v.y, nrm, ay);
    }

    float2 xv = xw2[(size_t)wid * 64 + lane];
    float2 b2 = ((const float2*)bias)[lane];
    float sl = dd * dd;
    float ox = fmaxf(fmaf(xv.x, sl, ax) + b2.x, 0.f);
    float oy = fmaxf(fmaf(xv.y, sl, ay) + b2.y, 0.f);
    float2 o; o.x = ox; o.y = oy;
    ((float2*)dest)[(size_t)wid * 64 + lane] = o;
}

// ---------------- fused MFMA GRU cell ----------------
// wih/whh: bf16 [384][128] row-major. 128 rows/block, 4 waves,
// 2 row-tiles/wave so every weight fragment feeds 2 MFMAs.
__global__ __launch_bounds__(256, 2) void gru_mfma_k(const float* __restrict__ X,
                                                     const float* __restrict__ Hs,
                                                     const short* __restrict__ wih,
                                                     const short* __restrict__ whh,
                                                     const float* __restrict__ bih,
                                                     const float* __restrict__ bhh,
                                                     float* __restrict__ out, int N) {
    int lane = threadIdx.x & 63;
    int row0 = blockIdx.x * 128 + (threadIdx.x >> 6) * 32;
    int lr = lane & 15, kg = lane >> 4;
    int ar0 = min(row0 + lr, N - 1);
    int ar1 = min(row0 + 16 + lr, N - 1);
    const float* x0 = X + (size_t)ar0 * DH;
    const float* x1 = X + (size_t)ar1 * DH;
    const float* h0 = Hs + (size_t)ar0 * DH;
    const float* h1p = Hs + (size_t)ar1 * DH;

    short8_t ax[2][4], ah[2][4];
#pragma unroll
    for (int ks = 0; ks < 4; ks++) {
        int ko = ks * 32 + kg * 8;
        ax[0][ks] = cvt8(x0 + ko);
        ax[1][ks] = cvt8(x1 + ko);
        ah[0][ks] = cvt8(h0 + ko);
        ah[1][ks] = cvt8(h1p + ko);
    }

    for (int cb = 0; cb < 4; cb++) {
        int c0 = cb * 32;
        f32x4 ai[3][2][2], ha[3][2][2];   // [gate][hf][rowtile]
#pragma unroll
        for (int g = 0; g < 3; g++)
#pragma unroll
            for (int hf = 0; hf < 2; hf++)
#pragma unroll
                for (int rt = 0; rt < 2; rt++) {
                    ai[g][hf][rt] = (f32x4){0.f, 0.f, 0.f, 0.f};
                    ha[g][hf][rt] = (f32x4){0.f, 0.f, 0.f, 0.f};
                }
#pragma unroll
        for (int g = 0; g < 3; g++)
#pragma unroll
            for (int hf = 0; hf < 2; hf++) {
                const short* wi = wih + (size_t)(g * DH + c0 + hf * 16 + lr) * DH;
                const short* wh = whh + (size_t)(g * DH + c0 + hf * 16 + lr) * DH;
                short8_t bi[4], bh[4];
#pragma unroll
                for (int ks = 0; ks < 4; ks++) {
                    bi[ks] = *(const short8_t*)(wi + ks * 32 + kg * 8);
                    bh[ks] = *(const short8_t*)(wh + ks * 32 + kg * 8);
                }
#pragma unroll
                for (int ks = 0; ks < 4; ks++) {
                    ai[g][hf][0] = __builtin_amdgcn_mfma_f32_16x16x32_bf16(ax[0][ks], bi[ks], ai[g][hf][0], 0, 0, 0);
                    ai[g][hf][1] = __builtin_amdgcn_mfma_f32_16x16x32_bf16(ax[1][ks], bi[ks], ai[g][hf][1], 0, 0, 0);
                    ha[g][hf][0] = __builtin_amdgcn_mfma_f32_16x16x32_bf16(ah[0][ks], bh[ks], ha[g][hf][0], 0, 0, 0);
                    ha[g][hf][1] = __builtin_amdgcn_mfma_f32_16x16x32_bf16(ah[1][ks], bh[ks], ha[g][hf][1], 0, 0, 0);
                }
            }
        // epilogue: gates + blend
#pragma unroll
        for (int hf = 0; hf < 2; hf++) {
            int gcol = c0 + hf * 16 + lr;
            float br = bih[gcol], bz = bih[DH + gcol], bn = bih[2 * DH + gcol];
            float cr = bhh[gcol], cz = bhh[DH + gcol], cn = bhh[2 * DH + gcol];
#pragma unroll
            for (int rt = 0; rt < 2; rt++)
#pragma unroll
                for (int j = 0; j < 4; j++) {
                    int grow = row0 + rt * 16 + kg * 4 + j;
                    if (grow < N) {
                        float hv = Hs[(size_t)grow * DH + gcol];
                        float rr = ai[0][hf][rt][j] + br + ha[0][hf][rt][j] + cr;
                        float zz = ai[1][hf][rt][j] + bz + ha[1][hf][rt][j] + cz;
                        float r = 1.f / (1.f + __expf(-rr));
                        float z = 1.f / (1.f + __expf(-zz));
                        float n = tanhf(ai[2][hf][rt][j] + bn + r * (ha[2][hf][rt][j] + cn));
                        out[(size_t)grow * DH + gcol] = (1.f - z) * n + z * hv;
                    }
                }
        }
    }
}

extern "C" void kernel_launch(void* const* d_in, const int* in_sizes, int n_in,
                              void* d_out, int out_size, void* d_ws, size_t ws_size,
                              hipStream_t stream) {
    const float* x    = (const float*)d_in[0];
    const int*   ei   = (const int*)d_in[1];
    const float* h1   = (const float*)d_in[2];
    const float* h2   = (const float*)d_in[3];
    const float* h3   = (const float*)d_in[4];
    const float* g1w  = (const float*)d_in[5];
    const float* g1b  = (const float*)d_in[6];
    const float* g2w  = (const float*)d_in[7];
    const float* g2b  = (const float*)d_in[8];
    const float* wih1 = (const float*)d_in[9];
    const float* whh1 = (const float*)d_in[10];
    const float* bih1 = (const float*)d_in[11];
    const float* bhh1 = (const float*)d_in[12];
    const float* wih2 = (const float*)d_in[13];
    const float* whh2 = (const float*)d_in[14];
    const float* bih2 = (const float*)d_in[15];
    const float* bhh2 = (const float*)d_in[16];
    const float* wih3 = (const float*)d_in[17];
    const float* whh3 = (const float*)d_in[18];
    const float* bih3 = (const float*)d_in[19];
    const float* bhh3 = (const float*)d_in[20];

    int N = in_sizes[0] / DH;
    int E = in_sizes[1] / 2;
    int B = (N + SCB - 1) / SCB;

    char* wsp = (char*)d_ws;
    auto alloc = [&](size_t bytes) -> char* {
        char* p = wsp;
        wsp += (bytes + 63) & ~(size_t)63;
        return p;
    };
    unsigned* cnt = (unsigned*)alloc((size_t)N * 4);
    int* offs     = (int*)alloc(((size_t)N + 1) * 4);
    int* cur      = (int*)alloc((size_t)N * 4);
    float* dinv   = (float*)alloc((size_t)N * 4);
    unsigned* bsum= (unsigned*)alloc(((size_t)B + 1) * 4);
    int* csr_src  = (int*)alloc((size_t)E * 4);
    float* xw     = (float*)alloc((size_t)N * DH * 4);
    float* x2     = (float*)alloc((size_t)N * DH * 4);
    short* w1t    = (short*)alloc((size_t)DH * DH * 2);
    short* w2t    = (short*)alloc((size_t)DH * DH * 2);
    const int WN = 3 * DH * DH;      // 49152
    short* wbAll  = (short*)alloc((size_t)6 * WN * 2);
    short* wb[6];
    for (int i = 0; i < 6; i++) wb[i] = wbAll + (size_t)i * WN;

    float* out  = (float*)d_out;
    float* h1n  = out;
    float* h2n  = out + (size_t)N * DH;
    float* h3n  = out + 2 * (size_t)N * DH;

    // ---- weight prep (bf16) ----
    f2bf6_k<<<(6 * WN + 255) / 256, 256, 0, stream>>>(wih1, whh1, wih2, whh2, wih3, whh3, wbAll, WN);
    transpose_bf2_k<<<(2 * DH * DH + 255) / 256, 256, 0, stream>>>(g1w, g2w, w1t, w2t);

    // ---- CSR build (per call; deterministic) ----
    hipMemsetAsync(cnt, 0, (size_t)N * 4, stream);
    deg_count_k<<<(E + 255) / 256, 256, 0, stream>>>(ei, E, cnt);
    scan1_k<<<B, 256, 0, stream>>>(cnt, N, offs, bsum);
    scan2_k<<<1, 1024, 0, stream>>>(bsum, B);
    scan3_k<<<(N + 255) / 256, 256, 0, stream>>>(offs, cur, dinv, cnt, bsum, N, B);
    fill_k<<<(E + 255) / 256, 256, 0, stream>>>(ei, E, cur, csr_src);

    int nblk128 = (N + 127) / 128;
    int gblocks = (N + 3) / 4;

    // ---- GCN layer 1 ----
    gemm_mfma_k<<<nblk128, 256, 0, stream>>>(x, w1t, xw, N);
    gather_k<<<gblocks, 256, 0, stream>>>(csr_src, offs, dinv, xw, g1b, x2, N);

    // ---- GCN layer 2 ----
    gemm_mfma_k<<<nblk128, 256, 0, stream>>>(x2, w2t, xw, N);
    gather_k<<<gblocks, 256, 0, stream>>>(csr_src, offs, dinv, xw, g2b, x2, N);

    // ---- GRU chain ----
    gru_mfma_k<<<nblk128, 256, 0, stream>>>(x2,  h1, wb[0], wb[1], bih1, bhh1, h1n, N);
    gru_mfma_k<<<nblk128, 256, 0, stream>>>(h1n, h2, wb[2], wb[3], bih2, bhh2, h2n, N);
    gru_mfma_k<<<nblk128, 256, 0, stream>>>(h2n, h3, wb[4], wb[5], bih3, bhh3, h3n, N);
}